// Round 1
// baseline (245.947 us; speedup 1.0000x reference)
//
#include <hip/hip_runtime.h>

#define BN 32
#define BC 512
#define BH 64
#define BW 64
#define MIPD 16

// ---------------------------------------------------------------- kernel 1
// one block per (n,c): compute row means (over w) and col means (over h)
// of the 64x64 tile, write ycat[n][c][0:64]=rowmean, [64:128]=colmean.
__global__ __launch_bounds__(256) void k_means(const float* __restrict__ x,
                                               float* __restrict__ ycat) {
    int bc = blockIdx.x;                         // n*512 + c
    const float4* x4 = (const float4*)(x + (size_t)bc * (BH * BW));
    __shared__ float rowsum[64];
    __shared__ float colsum[64];
    __shared__ float colpart[256][5];            // +1 pad -> conflict-free
    int t = threadIdx.x;

    float cx = 0.f, cy = 0.f, cz = 0.f, cw = 0.f;
    for (int i = 0; i < 4; ++i) {
        int f = t + i * 256;                     // float4 index 0..1023
        float4 v = x4[f];
        // row reduction: 16 consecutive lanes share row h = f>>4
        float s = v.x + v.y + v.z + v.w;
        s += __shfl_down(s, 8, 16);
        s += __shfl_down(s, 4, 16);
        s += __shfl_down(s, 2, 16);
        s += __shfl_down(s, 1, 16);
        if ((t & 15) == 0) rowsum[f >> 4] = s;   // unique writer per h
        // column partials: thread t always owns columns (t&15)*4 .. +3
        cx += v.x; cy += v.y; cz += v.z; cw += v.w;
    }
    colpart[t][0] = cx; colpart[t][1] = cy; colpart[t][2] = cz; colpart[t][3] = cw;
    __syncthreads();
    if (t < 64) {
        int base = t >> 2, comp = t & 3;         // column t
        float s = 0.f;
        for (int g = 0; g < 16; ++g) s += colpart[base + 16 * g][comp];
        colsum[t] = s;
    }
    __syncthreads();
    if (t < 128) {
        float m = (t < 64 ? rowsum[t] : colsum[t - 64]) * (1.0f / 64.0f);
        ycat[(size_t)bc * 128 + t] = m;
    }
}

// ---------------------------------------------------------------- kernel 2
// one block per n: conv1 -> q/k/v -> scores -> softmax -> PV -> proj -> sigmoid
__global__ __launch_bounds__(256) void k_att(
    const float* __restrict__ ycat,
    const float* __restrict__ w_cv1, const float* __restrict__ b_cv1,
    const float* __restrict__ w_q, const float* __restrict__ b_q,
    const float* __restrict__ w_k, const float* __restrict__ b_k,
    const float* __restrict__ w_v, const float* __restrict__ b_v,
    const float* __restrict__ w_proj, const float* __restrict__ b_proj,
    float* __restrict__ yatt) {
    int n = blockIdx.x;
    int t = threadIdx.x;
    __shared__ float ych[64][128];   // 32 KB  c-chunk of ycat
    __shared__ float wch[16][64];    //  4 KB  w_cv1 chunk
    __shared__ float yl[16][128];    //  8 KB  conv1 output
    __shared__ float qs[16][64], ks[16][64], vs[16][64]; // 12 KB
    __shared__ float attn[64][65];   // 16.25 KB (+1 pad)
    __shared__ float zs[16][64];     //  4 KB

    // --- conv1: y[m][l] = sum_c w_cv1[m][c] * ycat[n][c][l] + b_cv1[m]
    float acc[8];
    for (int i = 0; i < 8; ++i) acc[i] = 0.f;
    const float* ybase = ycat + (size_t)n * (BC * 128);
    for (int cc = 0; cc < 8; ++cc) {             // chunks of 64 channels
        const float4* src = (const float4*)(ybase + cc * 64 * 128);
        float4* dst = (float4*)&ych[0][0];
        for (int i = 0; i < 8; ++i) dst[t + i * 256] = src[t + i * 256];
        for (int i = t; i < 1024; i += 256) {
            int m = i >> 6, j = i & 63;
            wch[m][j] = w_cv1[m * BC + cc * 64 + j];
        }
        __syncthreads();
        for (int k8 = 0; k8 < 8; ++k8) {
            int o = t + k8 * 256;
            int m = o >> 7, l = o & 127;
            float a = acc[k8];
            for (int j = 0; j < 64; ++j) a += wch[m][j] * ych[j][l];
            acc[k8] = a;
        }
        __syncthreads();
    }
    for (int k8 = 0; k8 < 8; ++k8) {
        int o = t + k8 * 256;
        int m = o >> 7, l = o & 127;
        yl[m][l] = acc[k8] + b_cv1[m];
    }
    __syncthreads();

    // --- q from yh (l<64), k/v from yw (l>=64)
    for (int i = 0; i < 4; ++i) {
        int o = t + i * 256;                     // 1024 = 16x64
        int d = o >> 6, hh = o & 63;
        float aq = b_q[d], ak = b_k[d], av = b_v[d];
        for (int m = 0; m < 16; ++m) {
            float wqm = w_q[d * 16 + m], wkm = w_k[d * 16 + m], wvm = w_v[d * 16 + m];
            aq += wqm * yl[m][hh];
            ak += wkm * yl[m][64 + hh];
            av += wvm * yl[m][64 + hh];
        }
        qs[d][hh] = aq; ks[d][hh] = ak; vs[d][hh] = av;
    }
    __syncthreads();

    // --- scores: attn[h][w] = 0.25 * sum_d q[d][h]*k[d][w]
    for (int i = 0; i < 16; ++i) {
        int o = t + i * 256;
        int hh = o >> 6, ww = o & 63;
        float s = 0.f;
        for (int d = 0; d < 16; ++d) s += qs[d][hh] * ks[d][ww];
        attn[hh][ww] = s * 0.25f;
    }
    __syncthreads();

    // --- softmax over w, 4 threads per row
    {
        int r = t >> 2, sub = t & 3;
        float mx = -1e30f;
        for (int j = 0; j < 16; ++j) mx = fmaxf(mx, attn[r][sub + 4 * j]);
        mx = fmaxf(mx, __shfl_xor(mx, 1, 4));
        mx = fmaxf(mx, __shfl_xor(mx, 2, 4));
        float sm = 0.f;
        for (int j = 0; j < 16; ++j) {
            float e = __expf(attn[r][sub + 4 * j] - mx);
            attn[r][sub + 4 * j] = e;
            sm += e;
        }
        sm += __shfl_xor(sm, 1, 4);
        sm += __shfl_xor(sm, 2, 4);
        float inv = 1.0f / sm;
        for (int j = 0; j < 16; ++j) attn[r][sub + 4 * j] *= inv;
    }
    __syncthreads();

    // --- z[d][h] = sum_w attn[h][w] * v[d][w]
    for (int i = 0; i < 4; ++i) {
        int o = t + i * 256;
        int d = o >> 6, hh = o & 63;
        float a = 0.f;
        for (int ww = 0; ww < 64; ++ww) a += attn[hh][ww] * vs[d][ww];
        zs[d][hh] = a;
    }
    __syncthreads();

    // --- proj + sigmoid: yatt[n][o][h]
    float* yo = yatt + (size_t)n * (BC * BH);
    for (int i = 0; i < 128; ++i) {
        int idx = t + i * 256;                   // 32768 = 512x64
        int o = idx >> 6, hh = idx & 63;
        float a = b_proj[o];
        for (int m = 0; m < 16; ++m) a += w_proj[o * 16 + m] * zs[m][hh];
        yo[idx] = 1.0f / (1.0f + __expf(-a));
    }
}

// ---------------------------------------------------------------- kernel 3
// out[n][c][h][w] = x[n][c][h][w] * yatt[n][c][h]
__global__ __launch_bounds__(256) void k_mul(const float* __restrict__ x,
                                             const float* __restrict__ yatt,
                                             float* __restrict__ out) {
    size_t nf4 = (size_t)BN * BC * BH * BW / 4;  // 16,777,216 float4
    size_t stride = (size_t)gridDim.x * 256;
    const float4* x4 = (const float4*)x;
    float4* o4 = (float4*)out;
    for (size_t f = (size_t)blockIdx.x * 256 + threadIdx.x; f < nf4; f += stride) {
        float g = yatt[f >> 4];                  // 16 float4 per (n,c,h) row
        float4 v = x4[f];
        v.x *= g; v.y *= g; v.z *= g; v.w *= g;
        o4[f] = v;
    }
}

extern "C" void kernel_launch(void* const* d_in, const int* in_sizes, int n_in,
                              void* d_out, int out_size, void* d_ws, size_t ws_size,
                              hipStream_t stream) {
    const float* x      = (const float*)d_in[0];
    const float* w_cv1  = (const float*)d_in[1];
    const float* b_cv1  = (const float*)d_in[2];
    const float* w_q    = (const float*)d_in[3];
    const float* b_q    = (const float*)d_in[4];
    const float* w_k    = (const float*)d_in[5];
    const float* b_k    = (const float*)d_in[6];
    const float* w_v    = (const float*)d_in[7];
    const float* b_v    = (const float*)d_in[8];
    const float* w_proj = (const float*)d_in[9];
    const float* b_proj = (const float*)d_in[10];
    float* out = (float*)d_out;

    float* ycat = (float*)d_ws;                        // 32*512*128 f32 = 8 MB
    float* yatt = ycat + (size_t)BN * BC * 128;        // 32*512*64  f32 = 4 MB

    hipLaunchKernelGGL(k_means, dim3(BN * BC), dim3(256), 0, stream, x, ycat);
    hipLaunchKernelGGL(k_att, dim3(BN), dim3(256), 0, stream,
                       ycat, w_cv1, b_cv1, w_q, b_q, w_k, b_k, w_v, b_v,
                       w_proj, b_proj, yatt);
    hipLaunchKernelGGL(k_mul, dim3(2048), dim3(256), 0, stream, x, yatt, out);
}

// Round 2
// 152.615 us; speedup vs baseline: 1.6116x; 1.6116x over previous
//
#include <hip/hip_runtime.h>

#define BN 32
#define BC 512
#define BH 64
#define BW 64

typedef float vf4 __attribute__((ext_vector_type(4)));

// ---------------------------------------------------------------- kernel 1
// one block per (n,c): row means (over w) and col means (over h) of the
// 64x64 tile -> ycat[n][c][0:64]=rowmean, [64:128]=colmean.
__global__ __launch_bounds__(256) void k_means(const float* __restrict__ x,
                                               float* __restrict__ ycat) {
    int bc = blockIdx.x;                         // n*512 + c
    const float4* x4 = (const float4*)(x + (size_t)bc * (BH * BW));
    __shared__ float rowsum[64];
    __shared__ float colsum[64];
    __shared__ float colpart[256][5];            // +1 pad -> conflict-free
    int t = threadIdx.x;

    float cx = 0.f, cy = 0.f, cz = 0.f, cw = 0.f;
    for (int i = 0; i < 4; ++i) {
        int f = t + i * 256;                     // float4 index 0..1023
        float4 v = x4[f];
        float s = v.x + v.y + v.z + v.w;         // 16 lanes share row f>>4
        s += __shfl_down(s, 8, 16);
        s += __shfl_down(s, 4, 16);
        s += __shfl_down(s, 2, 16);
        s += __shfl_down(s, 1, 16);
        if ((t & 15) == 0) rowsum[f >> 4] = s;
        cx += v.x; cy += v.y; cz += v.z; cw += v.w;   // cols (t&15)*4..+3
    }
    colpart[t][0] = cx; colpart[t][1] = cy; colpart[t][2] = cz; colpart[t][3] = cw;
    __syncthreads();
    if (t < 64) {
        int base = t >> 2, comp = t & 3;         // column t
        float s = 0.f;
        for (int g = 0; g < 16; ++g) s += colpart[base + 16 * g][comp];
        colsum[t] = s;
    }
    __syncthreads();
    if (t < 128) {
        float m = (t < 64 ? rowsum[t] : colsum[t - 64]) * (1.0f / 64.0f);
        ycat[(size_t)bc * 128 + t] = m;
    }
}

// ---------------------------------------------------------------- kernel 2
// one block per n: conv1 -> q/k/v -> scores -> softmax -> PV -> zbuf[n][16][64]
__global__ __launch_bounds__(256) void k_att(
    const float* __restrict__ ycat,
    const float* __restrict__ w_cv1, const float* __restrict__ b_cv1,
    const float* __restrict__ w_q, const float* __restrict__ b_q,
    const float* __restrict__ w_k, const float* __restrict__ b_k,
    const float* __restrict__ w_v, const float* __restrict__ b_v,
    float* __restrict__ zbuf) {
    int n = blockIdx.x;
    int t = threadIdx.x;
    __shared__ float ych[64][128];   // 32 KB  c-chunk of ycat
    __shared__ float wchT[64][16];   //  4 KB  w_cv1 chunk, transposed
    __shared__ float yl[16][128];    //  8 KB  conv1 output
    __shared__ float qs[16][64], ks[16][64], vs[16][64]; // 12 KB
    __shared__ float attn[64][65];   // 16.25 KB (+1 pad)

    // --- conv1: thread owns column l (two threads layers over m-halves)
    float acc[8];
    #pragma unroll
    for (int r = 0; r < 8; ++r) acc[r] = 0.f;
    int l = t & 127, mb = (t >> 7) * 8;
    const float* ybase = ycat + (size_t)n * (BC * 128);
    for (int cc = 0; cc < 8; ++cc) {             // chunks of 64 channels
        const float4* src = (const float4*)(ybase + cc * 64 * 128);
        float4* dst = (float4*)&ych[0][0];
        for (int i = 0; i < 8; ++i) dst[t + i * 256] = src[t + i * 256];
        for (int i = 0; i < 4; ++i) {
            int idx = t + i * 256;               // 1024 = 16m x 64c
            int m = idx >> 6, c = idx & 63;
            wchT[c][m] = w_cv1[m * BC + cc * 64 + c];
        }
        __syncthreads();
        for (int c = 0; c < 64; ++c) {
            float yv = ych[c][l];                // 2-way (free) LDS access
            #pragma unroll
            for (int r = 0; r < 8; ++r) acc[r] += wchT[c][mb + r] * yv; // bcast
        }
        __syncthreads();
    }
    #pragma unroll
    for (int r = 0; r < 8; ++r) yl[mb + r][l] = acc[r] + b_cv1[mb + r];
    __syncthreads();

    // --- q from yh (l<64), k/v from yw (l>=64)
    for (int i = 0; i < 4; ++i) {
        int o = t + i * 256;                     // 1024 = 16x64
        int d = o >> 6, hh = o & 63;             // d wave-uniform
        float aq = b_q[d], ak = b_k[d], av = b_v[d];
        for (int m = 0; m < 16; ++m) {
            aq += w_q[d * 16 + m] * yl[m][hh];
            ak += w_k[d * 16 + m] * yl[m][64 + hh];
            av += w_v[d * 16 + m] * yl[m][64 + hh];
        }
        qs[d][hh] = aq; ks[d][hh] = ak; vs[d][hh] = av;
    }
    __syncthreads();

    // --- scores: attn[h][w] = 0.25 * sum_d q[d][h]*k[d][w]
    for (int i = 0; i < 16; ++i) {
        int o = t + i * 256;
        int hh = o >> 6, ww = o & 63;
        float s = 0.f;
        for (int d = 0; d < 16; ++d) s += qs[d][hh] * ks[d][ww];
        attn[hh][ww] = s * 0.25f;
    }
    __syncthreads();

    // --- softmax over w, 4 threads per row
    {
        int r = t >> 2, sub = t & 3;
        float mx = -1e30f;
        for (int j = 0; j < 16; ++j) mx = fmaxf(mx, attn[r][sub + 4 * j]);
        mx = fmaxf(mx, __shfl_xor(mx, 1, 4));
        mx = fmaxf(mx, __shfl_xor(mx, 2, 4));
        float sm = 0.f;
        for (int j = 0; j < 16; ++j) {
            float e = __expf(attn[r][sub + 4 * j] - mx);
            attn[r][sub + 4 * j] = e;
            sm += e;
        }
        sm += __shfl_xor(sm, 1, 4);
        sm += __shfl_xor(sm, 2, 4);
        float inv = 1.0f / sm;
        for (int j = 0; j < 16; ++j) attn[r][sub + 4 * j] *= inv;
    }
    __syncthreads();

    // --- z[d][h] = sum_w attn[h][w] * v[d][w]  -> zbuf (coalesced)
    for (int i = 0; i < 4; ++i) {
        int o = t + i * 256;
        int d = o >> 6, hh = o & 63;
        float a = 0.f;
        for (int ww = 0; ww < 64; ++ww) a += attn[hh][ww] * vs[d][ww];
        zbuf[(size_t)n * 1024 + o] = a;
    }
}

// ---------------------------------------------------------------- kernel 3
// fused proj + sigmoid + gate-multiply. Block = (n, chunk of 4 channels).
// REVERSED block order: k_means left the tail of x freshest in the 256 MB
// Infinity Cache; reading backwards turns the 2nd x pass into L3 hits.
// Non-temporal stores keep `out` from evicting x.
__global__ __launch_bounds__(256) void k_gate(
    const float* __restrict__ x, const float* __restrict__ zbuf,
    const float* __restrict__ w_proj, const float* __restrict__ b_proj,
    float* __restrict__ out) {
    int rid = (int)gridDim.x - 1 - (int)blockIdx.x;  // reverse
    int n = rid >> 7, cc = rid & 127;                // 4 channels per block
    int t = threadIdx.x;
    __shared__ float z_s[16][64];
    __shared__ float gate_s[256];

    for (int i = 0; i < 4; ++i) {
        int idx = t + i * 256;
        ((float*)z_s)[idx] = zbuf[(size_t)n * 1024 + idx];
    }
    __syncthreads();
    {
        int c = cc * 4 + (t >> 6), hh = t & 63;      // c wave-uniform
        float a = b_proj[c];
        #pragma unroll
        for (int m = 0; m < 16; ++m) a += w_proj[c * 16 + m] * z_s[m][hh];
        gate_s[t] = 1.0f / (1.0f + __expf(-a));
    }
    __syncthreads();

    size_t base = (size_t)rid * 4096;                // float4 units
    const vf4* x4 = (const vf4*)x + base;
    vf4* o4 = (vf4*)out + base;
    for (int i = 0; i < 16; ++i) {
        int f = t + i * 256;
        float g = gate_s[f >> 4];                    // 16 float4 per (c,h) row
        vf4 v = x4[f];
        v *= g;
        __builtin_nontemporal_store(v, &o4[f]);
    }
}

extern "C" void kernel_launch(void* const* d_in, const int* in_sizes, int n_in,
                              void* d_out, int out_size, void* d_ws, size_t ws_size,
                              hipStream_t stream) {
    const float* x      = (const float*)d_in[0];
    const float* w_cv1  = (const float*)d_in[1];
    const float* b_cv1  = (const float*)d_in[2];
    const float* w_q    = (const float*)d_in[3];
    const float* b_q    = (const float*)d_in[4];
    const float* w_k    = (const float*)d_in[5];
    const float* b_k    = (const float*)d_in[6];
    const float* w_v    = (const float*)d_in[7];
    const float* b_v    = (const float*)d_in[8];
    const float* w_proj = (const float*)d_in[9];
    const float* b_proj = (const float*)d_in[10];
    float* out = (float*)d_out;

    float* ycat = (float*)d_ws;                        // 32*512*128 f32 = 8 MB
    float* zbuf = ycat + (size_t)BN * BC * 128;        // 32*16*64   f32 = 128 KB

    hipLaunchKernelGGL(k_means, dim3(BN * BC), dim3(256), 0, stream, x, ycat);
    hipLaunchKernelGGL(k_att, dim3(BN), dim3(256), 0, stream,
                       ycat, w_cv1, b_cv1, w_q, b_q, w_k, b_k, w_v, b_v, zbuf);
    hipLaunchKernelGGL(k_gate, dim3(BN * 128), dim3(256), 0, stream,
                       x, zbuf, w_proj, b_proj, out);
}